// Round 6
// baseline (1356.347 us; speedup 1.0000x reference)
//
#include <hip/hip_runtime.h>

// ---------------------------------------------------------------------------
// 3-dispatch pipeline (R6: fused convs with WAVE SPECIALIZATION):
//  prep_weights: fp32->bf16 + K-permute; w_stem extended with w_vproj (K=1056)
//  convfused : conv1+conv2+conv3, 512 thr, 64 samples/wg, grid 1024.
//    R5 failure: one wave holding Bf2(36)+Bf3(72)+aoff(18) > 128-VGPR cap
//    -> 1.7 GB spill. R6: waves 0-3 = producers (conv1+conv2, hold Bf2 only);
//    waves 4-7 = consumers (conv3, 32 ch each as 2 sequential 16-ch tiles,
//    B-frags RELOADED per chunk from L2-resident W3 (144 KB) -- never
//    co-resident with Bf2). C2 double-buffered in LDS (72 KB total, 2 wg/CU):
//      p1: conv1(c) || conv3-tile0(c-1);  p2: conv2(c)->C2[c&1] || tile1(c-1)
//    No wave's live set exceeds ~105 arch VGPRs.
//  stem_gru: stem GEMM (M=64,K=1056) + GRU + fc -- EXACT R4 code (182 us).
//  HISTORY (do not repeat): R1 bounds(256,4) -> 64 arch VGPR + 1.1 GB spill.
//  R2 2-pass phase B -> 0.77 GB spill. R3 conv grid x2 neutral. R4 LDS 57->49
//  neutral. R5 unified fused waves -> 1.7 GB spill. Spill tripwire: FETCH or
//  WRITE >100 MB above traffic model => revert.
// ---------------------------------------------------------------------------

typedef short bf8 __attribute__((ext_vector_type(8)));   // 8 x bf16
typedef float f4  __attribute__((ext_vector_type(4)));   // MFMA C/D

#define MFMA(a, b, c) __builtin_amdgcn_mfma_f32_16x16x32_bf16(a, b, c, 0, 0, 0)

#define W3_OFF    18432
#define WSTEM_OFF 92160          // [192][1056]
#define WIH_OFF   294912         // [576][192]
#define WHH_OFF   405504
#define W_TOTAL   516096
#define C3_OFF    (1 << 20)      // shorts; c3out [65536][1024]

__device__ __forceinline__ unsigned short f2bf(float f) {
    unsigned int u = __float_as_uint(f);
    u += 0x7fffu + ((u >> 16) & 1u);          // RNE
    return (unsigned short)(u >> 16);
}
__device__ __forceinline__ float bf2f(unsigned short h) {
    return __uint_as_float(((unsigned int)h) << 16);
}
__device__ __forceinline__ float lrelu(float v) { return v > 0.f ? v : 0.05f * v; }
__device__ __forceinline__ float sigm(float x) { return 1.f / (1.f + __expf(-x)); }
__device__ __forceinline__ float tanh_(float x) {
    float e = __expf(2.f * x);
    return 1.f - 2.f / (e + 1.f);
}

// ---- weight prep ----------------------------------------------------------
__global__ void prep_weights(const float* __restrict__ w2, const float* __restrict__ w3,
                             const float* __restrict__ wstem, const float* __restrict__ wvp,
                             const float* __restrict__ wih, const float* __restrict__ whh,
                             unsigned short* __restrict__ o) {
    int i = blockIdx.x * 256 + threadIdx.x;
    if (i >= W_TOTAL) return;
    float val;
    if (i < W3_OFF) {
        int n = i / 288, k = i - n * 288;
        val = w2[n * 288 + (k & 31) * 9 + (k >> 5)];
    } else if (i < WSTEM_OFF) {
        int d = i - W3_OFF;
        int n = d / 576, k = d - n * 576;
        val = w3[n * 576 + (k & 63) * 9 + (k >> 6)];
    } else if (i < WIH_OFF) {
        int d = i - WSTEM_OFF;
        int n = d / 1056, k = d - n * 1056;
        if (k < 1024)       val = wstem[(n << 10) + (k & 127) * 8 + (k >> 7)];
        else if (k < 1033)  val = wvp[n * 9 + (k - 1024)];
        else                val = 0.f;
    } else if (i < WHH_OFF) {
        val = wih[i - WIH_OFF];
    } else {
        val = whh[i - WHH_OFF];
    }
    o[i] = f2bf(val);
}

// ---- conv3 one 16-channel n-tile (consumer wave helper) -------------------
// Reloads its 18 B-frags from global (L2-hot W3) each call; A from LDS C2 buf.
__device__ __forceinline__ void conv3_tile(
    const unsigned short* lds, const unsigned short* __restrict__ ws,
    unsigned short* __restrict__ c3, int W0, int cp, int cw,
    int col, int quad, const int* aoff, int nt)
{
    const int abase = 12288 + (cp & 1) * 12288;
    const int nch = cw * 32 + nt * 16 + col;        // out channel 0..127
    const unsigned short* bp = ws + W3_OFF + nch * 576 + quad * 8;
    bf8 B[18];
    #pragma unroll
    for (int ks = 0; ks < 18; ++ks) B[ks] = *(const bf8*)(bp + ks * 32);
    f4 acc[4];
    #pragma unroll
    for (int mt = 0; mt < 4; ++mt) acc[mt] = (f4){0.f, 0.f, 0.f, 0.f};
    #pragma unroll
    for (int ks = 0; ks < 18; ++ks) {
        #pragma unroll
        for (int mt = 0; mt < 4; ++mt) {
            int sc = mt * 2 + (col >> 3);
            bf8 a = *(const bf8*)&lds[abase + sc * 1536 + aoff[ks]];
            acc[mt] = MFMA(a, B[ks], acc[mt]);
        }
    }
    const int Gl = cw * 4 + nt * 2 + (col >> 3);
    #pragma unroll
    for (int mt = 0; mt < 4; ++mt)
        #pragma unroll
        for (int r = 0; r < 4; ++r) {
            int m = quad * 4 + r;
            int sc = mt * 2 + (m >> 3), opos = m & 7;
            int srow = W0 + cp * 8 + sc;
            c3[(size_t)srow * 1024 + opos * 128 + ((Gl ^ (srow & 15)) << 3) + (col & 7)]
                = f2bf(lrelu(acc[mt][r]));
        }
}

// ---- K1: fused conv1+conv2+conv3, producer/consumer waves -----------------
// LDS shorts: C1 [0,12288) | C2 dbuf [12288,24576) and [24576,36864). 72 KB.
__global__ __launch_bounds__(512, 1) void convfused(
    const float* __restrict__ x, const float* __restrict__ w1,
    const unsigned short* __restrict__ ws, unsigned short* __restrict__ c3)
{
    __shared__ __align__(16) unsigned short lds[36864];
    const int tid = threadIdx.x;
    const int wave = tid >> 6, lane = tid & 63;
    const int col = lane & 15, quad = lane >> 4;
    const int W0 = blockIdx.x * 64;
    const int w4 = wave & 3, cw = wave - 4;

    // producer state: conv2 B-frags + K-permute map (waves 0-3 only)
    bf8 Bf2[9];
    int kq2[9];
    if (wave < 4) {
        #pragma unroll
        for (int ks = 0; ks < 9; ++ks) {
            int k0 = ks * 32 + quad * 8;
            Bf2[ks] = *(const bf8*)(ws + (w4 * 16 + col) * 288 + k0);
            int ky = k0 / 96, r = k0 - 96 * ky;
            kq2[ks] = (ky * 8 + (r >> 5)) * 32 + (r & 31);
        }
    }
    const int g = w4 * 2 + (col >> 3);              // conv2 store ch-group

    // lane-const conv3 A offsets, matching conv2's baked swizzle
    int aoff[18];
    {
        int opos = col & 7;
        int oy = opos >> 2, ox = opos & 3;
        int spar = (col >> 3) & 1;
        #pragma unroll
        for (int ks = 0; ks < 18; ++ks) {
            int k0 = ks * 32 + quad * 8;
            int b = k0 >> 6;
            int ky = b / 3, kx = b - 3 * ky;
            int pos2 = (oy + ky) * 6 + (ox + kx);
            int gg = (k0 & 63) >> 3;
            int key = (pos2 + (spar << 2)) & 7;
            aoff[ks] = pos2 * 64 + ((gg ^ key) << 3);
        }
    }

    for (int c = 0; c < 9; ++c) {
        // ---- p1: producers conv1(c) || consumers conv3-tile0(c-1) ----
        if (wave < 4) {
            if (c < 8 && tid < 192) {
                int sl0 = tid / 48, p = tid - sl0 * 48;
                int y = p >> 3, xx = p & 7;
                #pragma unroll
                for (int ss = 0; ss < 2; ++ss) {
                    int sl = sl0 + ss * 4;
                    const float* xp = x + (size_t)(W0 + c * 8 + sl) * 192 + y * 32 + xx * 2;
                    float x00 = xp[0], x01 = xp[1], x10 = xp[16], x11 = xp[17];
                    int base = sl * 1536, sw = (sl & 3) << 3;
                    #pragma unroll
                    for (int cc = 0; cc < 32; ++cc) {
                        int co = (cc + p) & 31;
                        float a = x00 * w1[co * 4] + x01 * w1[co * 4 + 1]
                                + x10 * w1[co * 4 + 2] + x11 * w1[co * 4 + 3];
                        lds[base + ((p * 32 + co) ^ sw)] = f2bf(lrelu(a));
                    }
                }
            }
        } else if (c > 0) {
            conv3_tile(lds, ws, c3, W0, c - 1, cw, col, quad, aoff, 0);
        }
        __syncthreads();

        // ---- p2: producers conv2(c)->C2[c&1] || consumers tile1(c-1) ----
        if (wave < 4) {
            if (c < 8) {
                const int wbase = 12288 + (c & 1) * 12288;
                #pragma unroll
                for (int sub = 0; sub < 2; ++sub) {
                    #pragma unroll
                    for (int mt2 = 0; mt2 < 3; ++mt2) {
                        int m0 = mt2 * 32 + col, m1 = m0 + 16;
                        int s0 = m0 & 3, p0 = m0 >> 2;
                        int s1 = m1 & 3, p1 = m1 >> 2;
                        int oy0 = p0 / 6, ox0 = p0 - 6 * oy0;
                        int oy1 = p1 / 6, ox1 = p1 - 6 * oy1;
                        int b0 = (sub * 4 + s0) * 1536, qb0 = (oy0 * 8 + ox0) * 32, sw0 = (s0 & 3) << 3;
                        int b1 = (sub * 4 + s1) * 1536, qb1 = (oy1 * 8 + ox1) * 32, sw1 = (s1 & 3) << 3;
                        f4 acc0 = {0.f, 0.f, 0.f, 0.f}, acc1 = {0.f, 0.f, 0.f, 0.f};
                        #pragma unroll
                        for (int ks = 0; ks < 9; ++ks) {
                            bf8 a0 = *(const bf8*)&lds[b0 + ((qb0 + kq2[ks]) ^ sw0)];
                            bf8 a1 = *(const bf8*)&lds[b1 + ((qb1 + kq2[ks]) ^ sw1)];
                            acc0 = MFMA(a0, Bf2[ks], acc0);
                            acc1 = MFMA(a1, Bf2[ks], acc1);
                        }
                        #pragma unroll
                        for (int r = 0; r < 4; ++r) {
                            int m = mt2 * 32 + quad * 4 + r;
                            int s = m & 3, pos = m >> 2;
                            int slc = sub * 4 + s;
                            int key = (pos + ((slc & 1) << 2)) & 7;
                            lds[wbase + slc * 1536 + pos * 64 + ((g ^ key) << 3) + (col & 7)]
                                = f2bf(lrelu(acc0[r]));
                            m += 16; s = m & 3; pos = m >> 2;
                            slc = sub * 4 + s;
                            key = (pos + ((slc & 1) << 2)) & 7;
                            lds[wbase + slc * 1536 + pos * 64 + ((g ^ key) << 3) + (col & 7)]
                                = f2bf(lrelu(acc1[r]));
                        }
                    }
                }
            }
        } else if (c > 0) {
            conv3_tile(lds, ws, c3, W0, c - 1, cw, col, quad, aoff, 1);
        }
        __syncthreads();
    }
}

// ---- K3: stem GEMM + GRU + fc --------------------------------------------
// 1024 wgs, M=64 samples/wg. LDS 48 KB: FUSED [0,12288) | A/HX [12288,24576).
// EXACT R4 code (182 us, VGPR 128, no spill). Do NOT restructure phases or
// tighten launch_bounds -- see history note at top of file.
__global__ __launch_bounds__(256, 2) void stem_gru(
    const unsigned short* __restrict__ ws, const float* __restrict__ v,
    const float* __restrict__ hx, const float* __restrict__ bvp,
    const float* __restrict__ bih, const float* __restrict__ bhh,
    const float* __restrict__ wfc, float* __restrict__ out)
{
    __shared__ __align__(16) unsigned short lds[24576];
    const int tid = threadIdx.x;
    const int wave = tid >> 6, lane = tid & 63;
    const int col = lane & 15, quad = lane >> 4;
    const int S0 = blockIdx.x * 64;
    const unsigned short* c3 = ws + C3_OFF;
    const unsigned short* wstem = ws + WSTEM_OFF;

    // ============ phase A: stem GEMM, K=1056 (v_proj fused as K-tail) ======
    f4 acc[4][3];
    #pragma unroll
    for (int mt = 0; mt < 4; ++mt)
        #pragma unroll
        for (int t = 0; t < 3; ++t) acc[mt][t] = (f4){0.f, 0.f, 0.f, 0.f};

    const int sm = tid >> 2, sq = tid & 3;
    const unsigned short* asrc = c3 + (size_t)(S0 + sm) * 1024 + sq * 32;

    #pragma unroll
    for (int i = 0; i < 4; ++i)
        *(bf8*)&lds[12288 + sm * 128 + sq * 32 + i * 8] = *(const bf8*)(asrc + i * 8);

    for (int kc = 0; kc < 8; ++kc) {
        __syncthreads();                           // stage visible
        bf8 nx[4];
        if (kc < 7) {
            const unsigned short* s2 = asrc + (kc + 1) * 128;
            #pragma unroll
            for (int i = 0; i < 4; ++i) nx[i] = *(const bf8*)(s2 + i * 8);
        }
        #pragma unroll
        for (int ks = 0; ks < 4; ++ks) {
            int kl = ks * 32 + quad * 8;
            int kk = kc * 128 + kl;
            bf8 b0 = *(const bf8*)(wstem + (wave * 48 + col) * 1056 + kk);
            bf8 b1 = *(const bf8*)(wstem + (wave * 48 + 16 + col) * 1056 + kk);
            bf8 b2 = *(const bf8*)(wstem + (wave * 48 + 32 + col) * 1056 + kk);
            #pragma unroll
            for (int mt = 0; mt < 4; ++mt) {
                int m = mt * 16 + col;
                bf8 a = *(const bf8*)&lds[12288 + m * 128 + (kl ^ ((m & 15) << 3))];
                acc[mt][0] = MFMA(a, b0, acc[mt][0]);
                acc[mt][1] = MFMA(a, b1, acc[mt][1]);
                acc[mt][2] = MFMA(a, b2, acc[mt][2]);
            }
        }
        __syncthreads();                           // reads done
        if (kc < 7) {
            #pragma unroll
            for (int i = 0; i < 4; ++i)
                *(bf8*)&lds[12288 + sm * 128 + sq * 32 + i * 8] = nx[i];
        }
    }

    // K-tail: v (9 cols, zero-padded to 32)
    if (tid < 64) {
        int m = tid;
        const float* vp = v + (size_t)(S0 + m) * 9;
        __align__(16) unsigned short tmp[32];
        #pragma unroll
        for (int i = 0; i < 9; ++i) tmp[i] = f2bf(vp[i]);
        #pragma unroll
        for (int i = 9; i < 32; ++i) tmp[i] = 0;
        #pragma unroll
        for (int gg = 0; gg < 4; ++gg) {
            int gp = gg ^ (m & 15);
            *(bf8*)&lds[12288 + m * 128 + gp * 8] = *(bf8*)&tmp[gg * 8];
        }
    }
    __syncthreads();
    {
        int kl = quad * 8;
        bf8 b0 = *(const bf8*)(wstem + (wave * 48 + col) * 1056 + 1024 + kl);
        bf8 b1 = *(const bf8*)(wstem + (wave * 48 + 16 + col) * 1056 + 1024 + kl);
        bf8 b2 = *(const bf8*)(wstem + (wave * 48 + 32 + col) * 1056 + 1024 + kl);
        #pragma unroll
        for (int mt = 0; mt < 4; ++mt) {
            int m = mt * 16 + col;
            bf8 a = *(const bf8*)&lds[12288 + m * 128 + (kl ^ ((m & 15) << 3))];
            acc[mt][0] = MFMA(a, b0, acc[mt][0]);
            acc[mt][1] = MFMA(a, b1, acc[mt][1]);
            acc[mt][2] = MFMA(a, b2, acc[mt][2]);
        }
    }

    // epilogue: + bias, lrelu -> FUSED
    #pragma unroll
    for (int t = 0; t < 3; ++t) {
        int n = wave * 48 + t * 16 + col;
        float bb = bvp[n];
        #pragma unroll
        for (int mt = 0; mt < 4; ++mt)
            #pragma unroll
            for (int r = 0; r < 4; ++r) {
                int m = mt * 16 + quad * 4 + r;
                lds[m * 192 + (n ^ ((m & 7) << 3))] = f2bf(lrelu(acc[mt][t][r] + bb));
            }
    }
    __syncthreads();

    // ============ phase B: GRU (R0 1-pass shape; hx tile at [12288,24576)) =
    {
        int m = tid >> 2, qq = tid & 3;
        const float* hp = hx + (size_t)(S0 + m) * 192 + qq * 48;
        #pragma unroll
        for (int i = 0; i < 6; ++i) {
            f4 d = *(const f4*)(hp + i * 8 + 0);
            f4 d2 = *(const f4*)(hp + i * 8 + 4);
            __align__(16) unsigned short tmp[8];
            #pragma unroll
            for (int u = 0; u < 4; ++u) { tmp[u] = f2bf(d[u]); tmp[4 + u] = f2bf(d2[u]); }
            int gg = qq * 6 + i, gp = gg ^ (m & 7);
            *(bf8*)&lds[12288 + m * 192 + gp * 8] = *(bf8*)tmp;
        }
    }
    __syncthreads();

    #pragma unroll
    for (int t = 0; t < 3; ++t) {
        int j0 = (wave * 3 + t) * 16;
        int j = j0 + col;
        const unsigned short* pih = ws + WIH_OFF + j * 192;
        const unsigned short* phh = ws + WHH_OFF + j * 192;
        f4 g0[4], g1[4], g2[4], g3[4], g4[4], g5[4];
        #pragma unroll
        for (int mt = 0; mt < 4; ++mt) {
            g0[mt] = (f4){0.f,0.f,0.f,0.f}; g1[mt] = g0[mt]; g2[mt] = g0[mt];
            g3[mt] = g0[mt]; g4[mt] = g0[mt]; g5[mt] = g0[mt];
        }
        #pragma unroll
        for (int ks = 0; ks < 6; ++ks) {
            int k0 = ks * 32 + quad * 8;
            bf8 bir = *(const bf8*)(pih + k0);
            bf8 bhr = *(const bf8*)(phh + k0);
            bf8 biz = *(const bf8*)(pih + 36864 + k0);
            bf8 bhz = *(const bf8*)(phh + 36864 + k0);
            bf8 bin = *(const bf8*)(pih + 73728 + k0);
            bf8 bhn = *(const bf8*)(phh + 73728 + k0);
            #pragma unroll
            for (int mt = 0; mt < 4; ++mt) {
                int m = mt * 16 + col;
                int off = m * 192 + (k0 ^ ((m & 7) << 3));
                bf8 aF = *(const bf8*)&lds[off];
                bf8 aH = *(const bf8*)&lds[12288 + off];
                g0[mt] = MFMA(aF, bir, g0[mt]);
                g1[mt] = MFMA(aH, bhr, g1[mt]);
                g2[mt] = MFMA(aF, biz, g2[mt]);
                g3[mt] = MFMA(aH, bhz, g3[mt]);
                g4[mt] = MFMA(aF, bin, g4[mt]);
                g5[mt] = MFMA(aH, bhn, g5[mt]);
            }
        }
        float b_ir = bih[j], b_iz = bih[192 + j], b_in = bih[384 + j];
        float b_hr = bhh[j], b_hz = bhh[192 + j], b_hn = bhh[384 + j];
        #pragma unroll
        for (int mt = 0; mt < 4; ++mt)
            #pragma unroll
            for (int r = 0; r < 4; ++r) {
                int s = mt * 16 + quad * 4 + r;
                float rg = sigm(g0[mt][r] + b_ir + g1[mt][r] + b_hr);
                float zg = sigm(g2[mt][r] + b_iz + g3[mt][r] + b_hz);
                float ng = tanh_(g4[mt][r] + b_in + rg * (g5[mt][r] + b_hn));
                float hxv = hx[(size_t)(S0 + s) * 192 + j];
                float hnew = (1.f - zg) * ng + zg * hxv;
                out[65536 * 4 + (size_t)(S0 + s) * 192 + j] = hnew;
            }
    }
    __syncthreads();   // drain hnew stores (vmcnt(0) before barrier)

    // fc head: thread (s = tid&63, a = tid>>6), re-reads hnew from out (L2-hot)
    {
        int s = tid & 63, a = tid >> 6;
        const float* hp = out + 65536 * 4 + (size_t)(S0 + s) * 192;
        const float* wf = wfc + a * 192;
        float sum = 0.f;
        #pragma unroll 4
        for (int jj = 0; jj < 48; ++jj) {
            f4 hv = *(const f4*)(hp + jj * 4);
            f4 wv = *(const f4*)(wf + jj * 4);
            #pragma unroll
            for (int u = 0; u < 4; ++u) sum += lrelu(hv[u]) * wv[u];
        }
        out[(size_t)(S0 + s) * 4 + a] = sum;
    }
}

// ---------------------------------------------------------------------------
extern "C" void kernel_launch(void* const* d_in, const int* in_sizes, int n_in,
                              void* d_out, int out_size, void* d_ws, size_t ws_size,
                              hipStream_t stream) {
    const float* x     = (const float*)d_in[0];
    const float* v     = (const float*)d_in[1];
    const float* hx    = (const float*)d_in[2];
    const float* w1    = (const float*)d_in[3];
    const float* w2    = (const float*)d_in[4];
    const float* w3    = (const float*)d_in[5];
    const float* wstem = (const float*)d_in[6];
    const float* wvp   = (const float*)d_in[7];
    const float* bvp   = (const float*)d_in[8];
    const float* wih   = (const float*)d_in[9];
    const float* whh   = (const float*)d_in[10];
    const float* bih   = (const float*)d_in[11];
    const float* bhh   = (const float*)d_in[12];
    const float* wfc   = (const float*)d_in[13];
    unsigned short* wsp = (unsigned short*)d_ws;
    unsigned short* c3  = wsp + C3_OFF;

    prep_weights<<<2016, 256, 0, stream>>>(w2, w3, wstem, wvp, wih, whh, wsp);
    convfused<<<1024, 512, 0, stream>>>(x, w1, wsp, c3);
    stem_gru<<<1024, 256, 0, stream>>>(wsp, v, hx, bvp, bih, bhh, wfc, (float*)d_out);
}

// Round 7
// 1304.728 us; speedup vs baseline: 1.0396x; 1.0396x over previous
//
#include <hip/hip_runtime.h>

// ---------------------------------------------------------------------------
// 3-dispatch pipeline (R7: fused convs, register-liveness fix):
//  prep_weights: fp32->bf16 + K-permute; w_stem extended with w_vproj (K=1056)
//  convfused : conv1+conv2+conv3, 512 thr, 64 samples/wg, grid 1024.
//    R5: unified waves held Bf2+Bf3+aoff -> 1.7 GB spill.
//    R6: wave-specialized BUT Bf2/kq2 initialized BEFORE the chunk loop ->
//        live range spans every conv3_tile call -> allocator still over 128
//        (and aoff[] passed by pointer = address-taken, scratch risk) ->
//        1.0 GB junk traffic, 1094 us.
//    R7 fixes (math identical to R6, which PASSED numerically):
//      * Bf2/kq2 reloaded per chunk INSIDE producer p2 branch (45 regs
//        confined; W2 is L2-hot, 9 KB/wave/chunk; kq2 constant-folds).
//      * conv3_tile computes A-offsets inline (no address-taken array;
//        b=ks>>1 compile-time) and loads B in two scoped 9-frag halves.
//      Peak live set ~75 VGPR producer / ~75 consumer, vs 128 cap.
//  stem_gru: stem GEMM (M=64,K=1056) + GRU + fc -- EXACT R4 code (182 us).
//  HISTORY: R1 bounds(256,4) -> spill. R2 2-pass B -> spill. R3 grid x2
//  neutral. R4 LDS 57->49 neutral. Tripwire: convfused FETCH or WRITE
//  > 350 MB => spill persists => revert to split convs (583 us baseline).
// ---------------------------------------------------------------------------

typedef short bf8 __attribute__((ext_vector_type(8)));   // 8 x bf16
typedef float f4  __attribute__((ext_vector_type(4)));   // MFMA C/D

#define MFMA(a, b, c) __builtin_amdgcn_mfma_f32_16x16x32_bf16(a, b, c, 0, 0, 0)

#define W3_OFF    18432
#define WSTEM_OFF 92160          // [192][1056]
#define WIH_OFF   294912         // [576][192]
#define WHH_OFF   405504
#define W_TOTAL   516096
#define C3_OFF    (1 << 20)      // shorts; c3out [65536][1024]

__device__ __forceinline__ unsigned short f2bf(float f) {
    unsigned int u = __float_as_uint(f);
    u += 0x7fffu + ((u >> 16) & 1u);          // RNE
    return (unsigned short)(u >> 16);
}
__device__ __forceinline__ float bf2f(unsigned short h) {
    return __uint_as_float(((unsigned int)h) << 16);
}
__device__ __forceinline__ float lrelu(float v) { return v > 0.f ? v : 0.05f * v; }
__device__ __forceinline__ float sigm(float x) { return 1.f / (1.f + __expf(-x)); }
__device__ __forceinline__ float tanh_(float x) {
    float e = __expf(2.f * x);
    return 1.f - 2.f / (e + 1.f);
}

// ---- weight prep ----------------------------------------------------------
__global__ void prep_weights(const float* __restrict__ w2, const float* __restrict__ w3,
                             const float* __restrict__ wstem, const float* __restrict__ wvp,
                             const float* __restrict__ wih, const float* __restrict__ whh,
                             unsigned short* __restrict__ o) {
    int i = blockIdx.x * 256 + threadIdx.x;
    if (i >= W_TOTAL) return;
    float val;
    if (i < W3_OFF) {
        int n = i / 288, k = i - n * 288;
        val = w2[n * 288 + (k & 31) * 9 + (k >> 5)];
    } else if (i < WSTEM_OFF) {
        int d = i - W3_OFF;
        int n = d / 576, k = d - n * 576;
        val = w3[n * 576 + (k & 63) * 9 + (k >> 6)];
    } else if (i < WIH_OFF) {
        int d = i - WSTEM_OFF;
        int n = d / 1056, k = d - n * 1056;
        if (k < 1024)       val = wstem[(n << 10) + (k & 127) * 8 + (k >> 7)];
        else if (k < 1033)  val = wvp[n * 9 + (k - 1024)];
        else                val = 0.f;
    } else if (i < WHH_OFF) {
        val = wih[i - WIH_OFF];
    } else {
        val = whh[i - WHH_OFF];
    }
    o[i] = f2bf(val);
}

// ---- conv3 one 16-channel n-tile (consumer wave helper) -------------------
// B-frags reloaded from L2-hot W3 in two scoped 9-frag halves; A-offsets
// computed inline (b = ks>>1 is compile-time; ~7 VALU each, no arrays).
__device__ __forceinline__ void conv3_tile(
    const unsigned short* lds, const unsigned short* __restrict__ ws,
    unsigned short* __restrict__ c3, int W0, int cp, int cw,
    int col, int quad, int nt)
{
    const int abase = 12288 + (cp & 1) * 12288;
    const int nch = cw * 32 + nt * 16 + col;        // out channel 0..127
    const unsigned short* bp = ws + W3_OFF + nch * 576 + quad * 8;
    const int opos = col & 7;
    const int oy = opos >> 2, ox = opos & 3;
    const int spar = (col >> 3) & 1;
    const int scb = col >> 3;

    f4 acc[4];
    #pragma unroll
    for (int mt = 0; mt < 4; ++mt) acc[mt] = (f4){0.f, 0.f, 0.f, 0.f};

    #pragma unroll
    for (int kh = 0; kh < 2; ++kh) {
        bf8 B[9];                                   // scoped: halves can share regs
        #pragma unroll
        for (int j = 0; j < 9; ++j)
            B[j] = *(const bf8*)(bp + (kh * 9 + j) * 32);
        #pragma unroll
        for (int j = 0; j < 9; ++j) {
            const int ks = kh * 9 + j;              // compile-time
            const int k0 = ks * 32 + quad * 8;
            const int b = ks >> 1;                  // == k0>>6 (quad*8 < 32)
            const int ky = b / 3, kx = b - 3 * ky;  // compile-time
            const int pos2 = (oy + ky) * 6 + (ox + kx);
            const int gg = (k0 & 63) >> 3;          // (ks&1)*4 + quad
            const int key = (pos2 + (spar << 2)) & 7;
            const int aoffj = pos2 * 64 + ((gg ^ key) << 3);
            #pragma unroll
            for (int mt = 0; mt < 4; ++mt) {
                const int sc = mt * 2 + scb;
                bf8 a = *(const bf8*)&lds[abase + sc * 1536 + aoffj];
                acc[mt] = MFMA(a, B[j], acc[mt]);
            }
        }
    }

    const int Gl = cw * 4 + nt * 2 + scb;
    #pragma unroll
    for (int mt = 0; mt < 4; ++mt)
        #pragma unroll
        for (int r = 0; r < 4; ++r) {
            int m = quad * 4 + r;
            int sc = mt * 2 + (m >> 3), opos2 = m & 7;
            int srow = W0 + cp * 8 + sc;
            c3[(size_t)srow * 1024 + opos2 * 128 + ((Gl ^ (srow & 15)) << 3) + (col & 7)]
                = f2bf(lrelu(acc[mt][r]));
        }
}

// ---- K1: fused conv1+conv2+conv3, producer/consumer waves -----------------
// LDS shorts: C1 [0,12288) | C2 dbuf [12288,24576) and [24576,36864). 72 KB.
// p1: producers conv1(c) || consumers conv3-tile0(c-1)
// p2: producers conv2(c)->C2[c&1] || consumers conv3-tile1(c-1)
__global__ __launch_bounds__(512, 1) void convfused(
    const float* __restrict__ x, const float* __restrict__ w1,
    const unsigned short* __restrict__ ws, unsigned short* __restrict__ c3)
{
    __shared__ __align__(16) unsigned short lds[36864];
    const int tid = threadIdx.x;
    const int wave = tid >> 6, lane = tid & 63;
    const int col = lane & 15, quad = lane >> 4;
    const int W0 = blockIdx.x * 64;
    const int w4 = wave & 3, cw = wave - 4;
    const int g = w4 * 2 + (col >> 3);              // conv2 store ch-group

    for (int c = 0; c < 9; ++c) {
        // ---- p1: producers conv1(c) || consumers conv3-tile0(c-1) ----
        if (wave < 4) {
            if (c < 8 && tid < 192) {
                int sl0 = tid / 48, p = tid - sl0 * 48;
                int y = p >> 3, xx = p & 7;
                #pragma unroll
                for (int ss = 0; ss < 2; ++ss) {
                    int sl = sl0 + ss * 4;
                    const float* xp = x + (size_t)(W0 + c * 8 + sl) * 192 + y * 32 + xx * 2;
                    float x00 = xp[0], x01 = xp[1], x10 = xp[16], x11 = xp[17];
                    int base = sl * 1536, sw = (sl & 3) << 3;
                    #pragma unroll
                    for (int cc = 0; cc < 32; ++cc) {
                        int co = (cc + p) & 31;
                        float a = x00 * w1[co * 4] + x01 * w1[co * 4 + 1]
                                + x10 * w1[co * 4 + 2] + x11 * w1[co * 4 + 3];
                        lds[base + ((p * 32 + co) ^ sw)] = f2bf(lrelu(a));
                    }
                }
            }
        } else if (c > 0) {
            conv3_tile(lds, ws, c3, W0, c - 1, cw, col, quad, 0);
        }
        __syncthreads();

        // ---- p2: producers conv2(c)->C2[c&1] || consumers tile1(c-1) ----
        if (wave < 4) {
            if (c < 8) {
                // Bf2/kq2 loaded HERE (per chunk) so their live range is
                // confined to this branch -- the R6 spill fix.
                bf8 Bf2[9];
                int kq2[9];
                #pragma unroll
                for (int ks = 0; ks < 9; ++ks) {
                    int k0 = ks * 32 + quad * 8;
                    Bf2[ks] = *(const bf8*)(ws + (w4 * 16 + col) * 288 + k0);
                    kq2[ks] = ((ks / 3) * 8 + (ks % 3)) * 32 + quad * 8;
                }
                const int wbase = 12288 + (c & 1) * 12288;
                #pragma unroll
                for (int sub = 0; sub < 2; ++sub) {
                    #pragma unroll
                    for (int mt2 = 0; mt2 < 3; ++mt2) {
                        int m0 = mt2 * 32 + col, m1 = m0 + 16;
                        int s0 = m0 & 3, p0 = m0 >> 2;
                        int s1 = m1 & 3, p1 = m1 >> 2;
                        int oy0 = p0 / 6, ox0 = p0 - 6 * oy0;
                        int oy1 = p1 / 6, ox1 = p1 - 6 * oy1;
                        int b0 = (sub * 4 + s0) * 1536, qb0 = (oy0 * 8 + ox0) * 32, sw0 = (s0 & 3) << 3;
                        int b1 = (sub * 4 + s1) * 1536, qb1 = (oy1 * 8 + ox1) * 32, sw1 = (s1 & 3) << 3;
                        f4 acc0 = {0.f, 0.f, 0.f, 0.f}, acc1 = {0.f, 0.f, 0.f, 0.f};
                        #pragma unroll
                        for (int ks = 0; ks < 9; ++ks) {
                            bf8 a0 = *(const bf8*)&lds[b0 + ((qb0 + kq2[ks]) ^ sw0)];
                            bf8 a1 = *(const bf8*)&lds[b1 + ((qb1 + kq2[ks]) ^ sw1)];
                            acc0 = MFMA(a0, Bf2[ks], acc0);
                            acc1 = MFMA(a1, Bf2[ks], acc1);
                        }
                        #pragma unroll
                        for (int r = 0; r < 4; ++r) {
                            int m = mt2 * 32 + quad * 4 + r;
                            int s = m & 3, pos = m >> 2;
                            int slc = sub * 4 + s;
                            int key = (pos + ((slc & 1) << 2)) & 7;
                            lds[wbase + slc * 1536 + pos * 64 + ((g ^ key) << 3) + (col & 7)]
                                = f2bf(lrelu(acc0[r]));
                            m += 16; s = m & 3; pos = m >> 2;
                            slc = sub * 4 + s;
                            key = (pos + ((slc & 1) << 2)) & 7;
                            lds[wbase + slc * 1536 + pos * 64 + ((g ^ key) << 3) + (col & 7)]
                                = f2bf(lrelu(acc1[r]));
                        }
                    }
                }
            }
        } else if (c > 0) {
            conv3_tile(lds, ws, c3, W0, c - 1, cw, col, quad, 1);
        }
        __syncthreads();
    }
}

// ---- K3: stem GEMM + GRU + fc --------------------------------------------
// 1024 wgs, M=64 samples/wg. LDS 48 KB: FUSED [0,12288) | A/HX [12288,24576).
// EXACT R4 code (182 us, VGPR 128, no spill). Do NOT restructure phases or
// tighten launch_bounds -- see history note at top of file.
__global__ __launch_bounds__(256, 2) void stem_gru(
    const unsigned short* __restrict__ ws, const float* __restrict__ v,
    const float* __restrict__ hx, const float* __restrict__ bvp,
    const float* __restrict__ bih, const float* __restrict__ bhh,
    const float* __restrict__ wfc, float* __restrict__ out)
{
    __shared__ __align__(16) unsigned short lds[24576];
    const int tid = threadIdx.x;
    const int wave = tid >> 6, lane = tid & 63;
    const int col = lane & 15, quad = lane >> 4;
    const int S0 = blockIdx.x * 64;
    const unsigned short* c3 = ws + C3_OFF;
    const unsigned short* wstem = ws + WSTEM_OFF;

    // ============ phase A: stem GEMM, K=1056 (v_proj fused as K-tail) ======
    f4 acc[4][3];
    #pragma unroll
    for (int mt = 0; mt < 4; ++mt)
        #pragma unroll
        for (int t = 0; t < 3; ++t) acc[mt][t] = (f4){0.f, 0.f, 0.f, 0.f};

    const int sm = tid >> 2, sq = tid & 3;
    const unsigned short* asrc = c3 + (size_t)(S0 + sm) * 1024 + sq * 32;

    #pragma unroll
    for (int i = 0; i < 4; ++i)
        *(bf8*)&lds[12288 + sm * 128 + sq * 32 + i * 8] = *(const bf8*)(asrc + i * 8);

    for (int kc = 0; kc < 8; ++kc) {
        __syncthreads();                           // stage visible
        bf8 nx[4];
        if (kc < 7) {
            const unsigned short* s2 = asrc + (kc + 1) * 128;
            #pragma unroll
            for (int i = 0; i < 4; ++i) nx[i] = *(const bf8*)(s2 + i * 8);
        }
        #pragma unroll
        for (int ks = 0; ks < 4; ++ks) {
            int kl = ks * 32 + quad * 8;
            int kk = kc * 128 + kl;
            bf8 b0 = *(const bf8*)(wstem + (wave * 48 + col) * 1056 + kk);
            bf8 b1 = *(const bf8*)(wstem + (wave * 48 + 16 + col) * 1056 + kk);
            bf8 b2 = *(const bf8*)(wstem + (wave * 48 + 32 + col) * 1056 + kk);
            #pragma unroll
            for (int mt = 0; mt < 4; ++mt) {
                int m = mt * 16 + col;
                bf8 a = *(const bf8*)&lds[12288 + m * 128 + (kl ^ ((m & 15) << 3))];
                acc[mt][0] = MFMA(a, b0, acc[mt][0]);
                acc[mt][1] = MFMA(a, b1, acc[mt][1]);
                acc[mt][2] = MFMA(a, b2, acc[mt][2]);
            }
        }
        __syncthreads();                           // reads done
        if (kc < 7) {
            #pragma unroll
            for (int i = 0; i < 4; ++i)
                *(bf8*)&lds[12288 + sm * 128 + sq * 32 + i * 8] = nx[i];
        }
    }

    // K-tail: v (9 cols, zero-padded to 32)
    if (tid < 64) {
        int m = tid;
        const float* vp = v + (size_t)(S0 + m) * 9;
        __align__(16) unsigned short tmp[32];
        #pragma unroll
        for (int i = 0; i < 9; ++i) tmp[i] = f2bf(vp[i]);
        #pragma unroll
        for (int i = 9; i < 32; ++i) tmp[i] = 0;
        #pragma unroll
        for (int gg = 0; gg < 4; ++gg) {
            int gp = gg ^ (m & 15);
            *(bf8*)&lds[12288 + m * 128 + gp * 8] = *(bf8*)&tmp[gg * 8];
        }
    }
    __syncthreads();
    {
        int kl = quad * 8;
        bf8 b0 = *(const bf8*)(wstem + (wave * 48 + col) * 1056 + 1024 + kl);
        bf8 b1 = *(const bf8*)(wstem + (wave * 48 + 16 + col) * 1056 + 1024 + kl);
        bf8 b2 = *(const bf8*)(wstem + (wave * 48 + 32 + col) * 1056 + 1024 + kl);
        #pragma unroll
        for (int mt = 0; mt < 4; ++mt) {
            int m = mt * 16 + col;
            bf8 a = *(const bf8*)&lds[12288 + m * 128 + (kl ^ ((m & 15) << 3))];
            acc[mt][0] = MFMA(a, b0, acc[mt][0]);
            acc[mt][1] = MFMA(a, b1, acc[mt][1]);
            acc[mt][2] = MFMA(a, b2, acc[mt][2]);
        }
    }

    // epilogue: + bias, lrelu -> FUSED
    #pragma unroll
    for (int t = 0; t < 3; ++t) {
        int n = wave * 48 + t * 16 + col;
        float bb = bvp[n];
        #pragma unroll
        for (int mt = 0; mt < 4; ++mt)
            #pragma unroll
            for (int r = 0; r < 4; ++r) {
                int m = mt * 16 + quad * 4 + r;
                lds[m * 192 + (n ^ ((m & 7) << 3))] = f2bf(lrelu(acc[mt][t][r] + bb));
            }
    }
    __syncthreads();

    // ============ phase B: GRU (R0 1-pass shape; hx tile at [12288,24576)) =
    {
        int m = tid >> 2, qq = tid & 3;
        const float* hp = hx + (size_t)(S0 + m) * 192 + qq * 48;
        #pragma unroll
        for (int i = 0; i < 6; ++i) {
            f4 d = *(const f4*)(hp + i * 8 + 0);
            f4 d2 = *(const f4*)(hp + i * 8 + 4);
            __align__(16) unsigned short tmp[8];
            #pragma unroll
            for (int u = 0; u < 4; ++u) { tmp[u] = f2bf(d[u]); tmp[4 + u] = f2bf(d2[u]); }
            int gg = qq * 6 + i, gp = gg ^ (m & 7);
            *(bf8*)&lds[12288 + m * 192 + gp * 8] = *(bf8*)tmp;
        }
    }
    __syncthreads();

    #pragma unroll
    for (int t = 0; t < 3; ++t) {
        int j0 = (wave * 3 + t) * 16;
        int j = j0 + col;
        const unsigned short* pih = ws + WIH_OFF + j * 192;
        const unsigned short* phh = ws + WHH_OFF + j * 192;
        f4 g0[4], g1[4], g2[4], g3[4], g4[4], g5[4];
        #pragma unroll
        for (int mt = 0; mt < 4; ++mt) {
            g0[mt] = (f4){0.f,0.f,0.f,0.f}; g1[mt] = g0[mt]; g2[mt] = g0[mt];
            g3[mt] = g0[mt]; g4[mt] = g0[mt]; g5[mt] = g0[mt];
        }
        #pragma unroll
        for (int ks = 0; ks < 6; ++ks) {
            int k0 = ks * 32 + quad * 8;
            bf8 bir = *(const bf8*)(pih + k0);
            bf8 bhr = *(const bf8*)(phh + k0);
            bf8 biz = *(const bf8*)(pih + 36864 + k0);
            bf8 bhz = *(const bf8*)(phh + 36864 + k0);
            bf8 bin = *(const bf8*)(pih + 73728 + k0);
            bf8 bhn = *(const bf8*)(phh + 73728 + k0);
            #pragma unroll
            for (int mt = 0; mt < 4; ++mt) {
                int m = mt * 16 + col;
                int off = m * 192 + (k0 ^ ((m & 7) << 3));
                bf8 aF = *(const bf8*)&lds[off];
                bf8 aH = *(const bf8*)&lds[12288 + off];
                g0[mt] = MFMA(aF, bir, g0[mt]);
                g1[mt] = MFMA(aH, bhr, g1[mt]);
                g2[mt] = MFMA(aF, biz, g2[mt]);
                g3[mt] = MFMA(aH, bhz, g3[mt]);
                g4[mt] = MFMA(aF, bin, g4[mt]);
                g5[mt] = MFMA(aH, bhn, g5[mt]);
            }
        }
        float b_ir = bih[j], b_iz = bih[192 + j], b_in = bih[384 + j];
        float b_hr = bhh[j], b_hz = bhh[192 + j], b_hn = bhh[384 + j];
        #pragma unroll
        for (int mt = 0; mt < 4; ++mt)
            #pragma unroll
            for (int r = 0; r < 4; ++r) {
                int s = mt * 16 + quad * 4 + r;
                float rg = sigm(g0[mt][r] + b_ir + g1[mt][r] + b_hr);
                float zg = sigm(g2[mt][r] + b_iz + g3[mt][r] + b_hz);
                float ng = tanh_(g4[mt][r] + b_in + rg * (g5[mt][r] + b_hn));
                float hxv = hx[(size_t)(S0 + s) * 192 + j];
                float hnew = (1.f - zg) * ng + zg * hxv;
                out[65536 * 4 + (size_t)(S0 + s) * 192 + j] = hnew;
            }
    }
    __syncthreads();   // drain hnew stores (vmcnt(0) before barrier)

    // fc head: thread (s = tid&63, a = tid>>6), re-reads hnew from out (L2-hot)
    {
        int s = tid & 63, a = tid >> 6;
        const float* hp = out + 65536 * 4 + (size_t)(S0 + s) * 192;
        const float* wf = wfc + a * 192;
        float sum = 0.f;
        #pragma unroll 4
        for (int jj = 0; jj < 48; ++jj) {
            f4 hv = *(const f4*)(hp + jj * 4);
            f4 wv = *(const f4*)(wf + jj * 4);
            #pragma unroll
            for (int u = 0; u < 4; ++u) sum += lrelu(hv[u]) * wv[u];
        }
        out[(size_t)(S0 + s) * 4 + a] = sum;
    }
}

// ---------------------------------------------------------------------------
extern "C" void kernel_launch(void* const* d_in, const int* in_sizes, int n_in,
                              void* d_out, int out_size, void* d_ws, size_t ws_size,
                              hipStream_t stream) {
    const float* x     = (const float*)d_in[0];
    const float* v     = (const float*)d_in[1];
    const float* hx    = (const float*)d_in[2];
    const float* w1    = (const float*)d_in[3];
    const float* w2    = (const float*)d_in[4];
    const float* w3    = (const float*)d_in[5];
    const float* wstem = (const float*)d_in[6];
    const float* wvp   = (const float*)d_in[7];
    const float* bvp   = (const float*)d_in[8];
    const float* wih   = (const float*)d_in[9];
    const float* whh   = (const float*)d_in[10];
    const float* bih   = (const float*)d_in[11];
    const float* bhh   = (const float*)d_in[12];
    const float* wfc   = (const float*)d_in[13];
    unsigned short* wsp = (unsigned short*)d_ws;
    unsigned short* c3  = wsp + C3_OFF;

    prep_weights<<<2016, 256, 0, stream>>>(w2, w3, wstem, wvp, wih, whh, wsp);
    convfused<<<1024, 512, 0, stream>>>(x, w1, wsp, c3);
    stem_gru<<<1024, 256, 0, stream>>>(wsp, v, hx, bvp, bih, bhh, wfc, (float*)d_out);
}

// Round 8
// 589.398 us; speedup vs baseline: 2.3012x; 2.2137x over previous
//
#include <hip/hip_runtime.h>

// ---------------------------------------------------------------------------
// 4-stage split pipeline (R8: fusion ABANDONED after R5/R6/R7 all spilled
// >800 MB regardless of structure; reverted to R3 split + store-coalescing):
//  prep_weights: fp32->bf16 + K-permute; w_stem extended with w_vproj (K=1056)
//  conv12 : conv1+conv2, 1024 wgs/quarter, 16 samples/wg.
//           R8: conv2 epilogue -> LDS C2 (same swizzled layout, verified in
//           R5-R7 numerically), then LINEAR 16B coalesced copy-out to c2q.
//           Replaces 384 scattered 2B global stores/lane with 12 16B stores.
//  conv3k : GEMM M=256(8/chunk),N=128(half/wg),K=576, 1024 wgs/quarter.
//           R8: c3 epilogue staged in LDS (slot=(Gl&7)^(srow&7)) then 16B
//           copy-out to byte-identical addresses (g0=(h^(srow>>3&1))*8).
//  stem_gru: EXACT R0 code (181-184 us, VGPR 128, spill-free). DO NOT TOUCH.
//  HISTORY (do not repeat): R1 bounds(256,4)->spill; R2 2-pass GRU->spill;
//  R3 conv grid x2 neutral; R4 LDS 57->49 neutral (occupancy not the lever);
//  R5/R6/R7 conv fusion -> 0.8-1.7 GB junk traffic, 2x slower. Tripwire:
//  any kernel FETCH/WRITE >100 MB above traffic model => revert that change.
// ---------------------------------------------------------------------------

typedef short bf8 __attribute__((ext_vector_type(8)));   // 8 x bf16
typedef float f4  __attribute__((ext_vector_type(4)));   // MFMA C/D

#define MFMA(a, b, c) __builtin_amdgcn_mfma_f32_16x16x32_bf16(a, b, c, 0, 0, 0)

#define W3_OFF    18432
#define WSTEM_OFF 92160          // [192][1056]
#define WIH_OFF   294912         // [576][192]
#define WHH_OFF   405504
#define W_TOTAL   516096
#define C3_OFF    (1 << 20)      // shorts; c3out [65536][1024]
#define C2Q_OFF   68157440       // shorts; c2 quarter [16384][24][64]

__device__ __forceinline__ unsigned short f2bf(float f) {
    unsigned int u = __float_as_uint(f);
    u += 0x7fffu + ((u >> 16) & 1u);          // RNE
    return (unsigned short)(u >> 16);
}
__device__ __forceinline__ float bf2f(unsigned short h) {
    return __uint_as_float(((unsigned int)h) << 16);
}
__device__ __forceinline__ float lrelu(float v) { return v > 0.f ? v : 0.05f * v; }
__device__ __forceinline__ float sigm(float x) { return 1.f / (1.f + __expf(-x)); }
__device__ __forceinline__ float tanh_(float x) {
    float e = __expf(2.f * x);
    return 1.f - 2.f / (e + 1.f);
}

// ---- weight prep ----------------------------------------------------------
__global__ void prep_weights(const float* __restrict__ w2, const float* __restrict__ w3,
                             const float* __restrict__ wstem, const float* __restrict__ wvp,
                             const float* __restrict__ wih, const float* __restrict__ whh,
                             unsigned short* __restrict__ o) {
    int i = blockIdx.x * 256 + threadIdx.x;
    if (i >= W_TOTAL) return;
    float val;
    if (i < W3_OFF) {
        int n = i / 288, k = i - n * 288;
        val = w2[n * 288 + (k & 31) * 9 + (k >> 5)];
    } else if (i < WSTEM_OFF) {
        int d = i - W3_OFF;
        int n = d / 576, k = d - n * 576;
        val = w3[n * 576 + (k & 63) * 9 + (k >> 6)];
    } else if (i < WIH_OFF) {
        int d = i - WSTEM_OFF;
        int n = d / 1056, k = d - n * 1056;
        if (k < 1024)       val = wstem[(n << 10) + (k & 127) * 8 + (k >> 7)];
        else if (k < 1033)  val = wvp[n * 9 + (k - 1024)];
        else                val = 0.f;
    } else if (i < WHH_OFF) {
        val = wih[i - WIH_OFF];
    } else {
        val = whh[i - WHH_OFF];
    }
    o[i] = f2bf(val);
}

// ---- K1: conv1 + conv2 ----------------------------------------------------
// 1024 wgs/quarter, 16 samples/wg, 4 chunks of 4.
// LDS shorts: C1 [0,6144) | C2 [6144,12288). 24 KB.
__global__ __launch_bounds__(256, 2) void conv12(
    const float* __restrict__ x, const float* __restrict__ w1,
    const unsigned short* __restrict__ ws, unsigned short* __restrict__ c2q,
    int sbase)
{
    __shared__ __align__(16) unsigned short lds[12288];
    const int tid = threadIdx.x;
    const int wave = tid >> 6, lane = tid & 63;
    const int col = lane & 15, quad = lane >> 4;
    const int W0 = blockIdx.x * 16;                 // quarter-local sample base

    bf8 Bf2[9];
    int kq2[9];
    #pragma unroll
    for (int ks = 0; ks < 9; ++ks) {
        int k0 = ks * 32 + quad * 8;
        Bf2[ks] = *(const bf8*)(ws + (wave * 16 + col) * 288 + k0);
        int ky = k0 / 96, r = k0 - 96 * ky;
        kq2[ks] = (ky * 8 + (r >> 5)) * 32 + (r & 31);
    }
    const int g = wave * 2 + (col >> 3);            // c2 store ch-group

    for (int c = 0; c < 4; ++c) {
        // conv1: 2x2 s2, 1->32ch -> C1 [s][p48][co32] swizzled
        if (tid < 192) {
            int s = tid / 48, p = tid - s * 48;
            int y = p >> 3, xx = p & 7;
            const float* xp = x + (size_t)(sbase + W0 + c * 4 + s) * 192 + y * 32 + xx * 2;
            float x00 = xp[0], x01 = xp[1], x10 = xp[16], x11 = xp[17];
            int base = s * 1536, sw = (s & 3) << 3;
            #pragma unroll
            for (int cc = 0; cc < 32; ++cc) {
                int co = (cc + p) & 31;
                float a = x00 * w1[co * 4] + x01 * w1[co * 4 + 1]
                        + x10 * w1[co * 4 + 2] + x11 * w1[co * 4 + 3];
                lds[base + ((p * 32 + co) ^ sw)] = f2bf(lrelu(a));
            }
        }
        __syncthreads();

        // conv2: M=96 (m=pos*4+s), N=64 (wave n-tile), K=288 -> LDS C2
        // (same swizzled layout as the old global c2q bytes; s&1 == sloc&1)
        #pragma unroll
        for (int mt2 = 0; mt2 < 3; ++mt2) {
            int m0 = mt2 * 32 + col, m1 = m0 + 16;
            int s0 = m0 & 3, p0 = m0 >> 2;
            int s1 = m1 & 3, p1 = m1 >> 2;
            int oy0 = p0 / 6, ox0 = p0 - 6 * oy0;
            int oy1 = p1 / 6, ox1 = p1 - 6 * oy1;
            int b0 = s0 * 1536, qb0 = (oy0 * 8 + ox0) * 32, sw0 = (s0 & 3) << 3;
            int b1 = s1 * 1536, qb1 = (oy1 * 8 + ox1) * 32, sw1 = (s1 & 3) << 3;
            f4 acc0 = {0.f, 0.f, 0.f, 0.f}, acc1 = {0.f, 0.f, 0.f, 0.f};
            #pragma unroll
            for (int ks = 0; ks < 9; ++ks) {
                bf8 a0 = *(const bf8*)&lds[b0 + ((qb0 + kq2[ks]) ^ sw0)];
                bf8 a1 = *(const bf8*)&lds[b1 + ((qb1 + kq2[ks]) ^ sw1)];
                acc0 = MFMA(a0, Bf2[ks], acc0);
                acc1 = MFMA(a1, Bf2[ks], acc1);
            }
            #pragma unroll
            for (int r = 0; r < 4; ++r) {
                int m = mt2 * 32 + quad * 4 + r;
                int s = m & 3, pos = m >> 2;
                int key = (pos + ((s & 1) << 2)) & 7;
                lds[6144 + s * 1536 + pos * 64 + ((g ^ key) << 3) + (col & 7)]
                    = f2bf(lrelu(acc0[r]));
                m += 16; s = m & 3; pos = m >> 2;
                key = (pos + ((s & 1) << 2)) & 7;
                lds[6144 + s * 1536 + pos * 64 + ((g ^ key) << 3) + (col & 7)]
                    = f2bf(lrelu(acc1[r]));
            }
        }
        __syncthreads();

        // copy-out: 6144 shorts -> c2q, LINEAR, 16B per store (coalesced).
        {
            unsigned short* dst = c2q + (size_t)(W0 + c * 4) * 1536;
            #pragma unroll
            for (int j = 0; j < 3; ++j) {
                int t = (j * 256 + tid) * 8;
                *(bf8*)(dst + t) = *(const bf8*)&lds[6144 + t];
            }
        }
        // no barrier needed here: next conv1 writes C1 (disjoint); its barrier
        // orders these C2 reads against the next chunk's C2 writes.
    }
}

// ---- K2: conv3 as GEMM ----------------------------------------------------
// 1024 wgs/quarter: sblk=bid>>1 (32 samples), h=bid&1 (N-half), 4 chunks of 8.
// LDS shorts: A [0,12288) | C3 stage [12288,16384). 32 KB.
__global__ __launch_bounds__(256, 2) void conv3k(
    const unsigned short* __restrict__ ws, const unsigned short* __restrict__ c2q,
    unsigned short* __restrict__ c3, int sbase)
{
    __shared__ __align__(16) unsigned short lds[16384];
    const int tid = threadIdx.x;
    const int wave = tid >> 6, lane = tid & 63;
    const int col = lane & 15, quad = lane >> 4;
    const int h = blockIdx.x & 1;
    const int Q0 = (blockIdx.x >> 1) * 32;          // quarter-local base
    const int n_in = h * 64 + wave * 16 + col;      // out channel 0..127

    bf8 Bf3[18];
    #pragma unroll
    for (int ks = 0; ks < 18; ++ks)
        Bf3[ks] = *(const bf8*)(ws + W3_OFF + n_in * 576 + ks * 32 + quad * 8);

    // lane-const A offsets (element units), matching K1's baked swizzle
    int aoff[18];
    {
        int opos = col & 7;
        int oy = opos >> 2, ox = opos & 3;
        int spar = (col >> 3) & 1;
        #pragma unroll
        for (int ks = 0; ks < 18; ++ks) {
            int k0 = ks * 32 + quad * 8;
            int b = k0 >> 6;
            int ky = b / 3, kx = b - 3 * ky;
            int pos2 = (oy + ky) * 6 + (ox + kx);
            int gg = (k0 & 63) >> 3;
            int key = (pos2 + (spar << 2)) & 7;
            aoff[ks] = pos2 * 64 + ((gg ^ key) << 3);
        }
    }
    const int Gl = h * 8 + wave * 2 + (col >> 3);

    for (int c = 0; c < 4; ++c) {
        // stage 8 samples, verbatim linear copy (48 shorts/thread)
        const unsigned short* s2 = c2q + (size_t)(Q0 + c * 8) * 1536 + tid * 48;
        #pragma unroll
        for (int i = 0; i < 6; ++i)
            *(bf8*)&lds[tid * 48 + i * 8] = *(const bf8*)(s2 + i * 8);
        __syncthreads();

        f4 acc[4];
        #pragma unroll
        for (int mt = 0; mt < 4; ++mt) acc[mt] = (f4){0.f, 0.f, 0.f, 0.f};
        #pragma unroll
        for (int ks = 0; ks < 18; ++ks) {
            #pragma unroll
            for (int mt = 0; mt < 4; ++mt) {
                int sc = mt * 2 + (col >> 3);
                bf8 a = *(const bf8*)&lds[sc * 1536 + aoff[ks]];
                acc[mt] = MFMA(a, Bf3[ks], acc[mt]);
            }
        }
        // epilogue: stage to LDS (relative slot within the wg's 8-group).
        // Global byte layout: opos*128 + ((Gl^(srow&15))<<3)+(col&7); since
        // Gl = h*8 + gl7, Gl^(srow&15) = (h^srow3)*8 + (gl7^(srow&7)).
        #pragma unroll
        for (int mt = 0; mt < 4; ++mt) {
            #pragma unroll
            for (int r = 0; r < 4; ++r) {
                int m = quad * 4 + r;
                int sc = mt * 2 + (m >> 3), opos = m & 7;
                int srow = Q0 + c * 8 + sc;         // srow&7 unaffected by sbase (mult of 16)
                int slot = (Gl & 7) ^ (srow & 7);
                lds[12288 + (sc * 8 + opos) * 64 + (slot << 3) + (col & 7)]
                    = f2bf(lrelu(acc[mt][r]));
            }
        }
        __syncthreads();

        // copy-out: 512 x 16B chunks to byte-identical c3 addresses.
        #pragma unroll
        for (int j = 0; j < 2; ++j) {
            int u = j * 256 + tid;                  // 0..511
            int sc = u >> 6, opos = (u >> 3) & 7, ch = u & 7;
            int srow = sbase + Q0 + c * 8 + sc;
            int g0 = (h ^ ((srow >> 3) & 1)) * 8;
            *(bf8*)(c3 + (size_t)srow * 1024 + opos * 128 + (g0 + ch) * 8)
                = *(const bf8*)&lds[12288 + u * 8];
        }
        // no barrier: next stage writes A region (disjoint from C3 stage);
        // next chunk's first barrier orders these reads vs next C3 writes.
    }
}

// ---- K3: stem GEMM + GRU + fc --------------------------------------------
// 1024 wgs, M=64 samples/wg. LDS: FUSED [0,12288) | A-dbuf [12288,28672).
// EXACT R0 code (181 us, VGPR 128, no spill). DO NOT restructure phases or
// tighten launch_bounds -- see history note at top of file.
__global__ __launch_bounds__(256, 2) void stem_gru(
    const unsigned short* __restrict__ ws, const float* __restrict__ v,
    const float* __restrict__ hx, const float* __restrict__ bvp,
    const float* __restrict__ bih, const float* __restrict__ bhh,
    const float* __restrict__ wfc, float* __restrict__ out)
{
    __shared__ __align__(16) unsigned short lds[28672];
    const int tid = threadIdx.x;
    const int wave = tid >> 6, lane = tid & 63;
    const int col = lane & 15, quad = lane >> 4;
    const int S0 = blockIdx.x * 64;
    const unsigned short* c3 = ws + C3_OFF;
    const unsigned short* wstem = ws + WSTEM_OFF;

    // ============ phase A: stem GEMM, K=1056 (v_proj fused as K-tail) ======
    f4 acc[4][3];
    #pragma unroll
    for (int mt = 0; mt < 4; ++mt)
        #pragma unroll
        for (int t = 0; t < 3; ++t) acc[mt][t] = (f4){0.f, 0.f, 0.f, 0.f};

    const int sm = tid >> 2, sq = tid & 3;
    const unsigned short* asrc = c3 + (size_t)(S0 + sm) * 1024 + sq * 32;

    #pragma unroll
    for (int i = 0; i < 4; ++i)
        *(bf8*)&lds[12288 + sm * 128 + sq * 32 + i * 8] = *(const bf8*)(asrc + i * 8);
    __syncthreads();

    for (int kc = 0; kc < 8; ++kc) {
        bf8 nx[4];
        if (kc < 7) {
            const unsigned short* s2 = asrc + (kc + 1) * 128;
            #pragma unroll
            for (int i = 0; i < 4; ++i) nx[i] = *(const bf8*)(s2 + i * 8);
        }
        int abase = 12288 + (kc & 1) * 8192;
        #pragma unroll
        for (int ks = 0; ks < 4; ++ks) {
            int kl = ks * 32 + quad * 8;
            int kk = kc * 128 + kl;
            bf8 b0 = *(const bf8*)(wstem + (wave * 48 + col) * 1056 + kk);
            bf8 b1 = *(const bf8*)(wstem + (wave * 48 + 16 + col) * 1056 + kk);
            bf8 b2 = *(const bf8*)(wstem + (wave * 48 + 32 + col) * 1056 + kk);
            #pragma unroll
            for (int mt = 0; mt < 4; ++mt) {
                int m = mt * 16 + col;
                bf8 a = *(const bf8*)&lds[abase + m * 128 + (kl ^ ((m & 15) << 3))];
                acc[mt][0] = MFMA(a, b0, acc[mt][0]);
                acc[mt][1] = MFMA(a, b1, acc[mt][1]);
                acc[mt][2] = MFMA(a, b2, acc[mt][2]);
            }
        }
        if (kc < 7) {
            int wb = 12288 + ((kc + 1) & 1) * 8192;
            #pragma unroll
            for (int i = 0; i < 4; ++i)
                *(bf8*)&lds[wb + sm * 128 + sq * 32 + i * 8] = nx[i];
        }
        __syncthreads();
    }

    // K-tail: v (9 cols, zero-padded to 32) into buf0
    if (tid < 64) {
        int m = tid;
        const float* vp = v + (size_t)(S0 + m) * 9;
        __align__(16) unsigned short tmp[32];
        #pragma unroll
        for (int i = 0; i < 9; ++i) tmp[i] = f2bf(vp[i]);
        #pragma unroll
        for (int i = 9; i < 32; ++i) tmp[i] = 0;
        #pragma unroll
        for (int gg = 0; gg < 4; ++gg) {
            int gp = gg ^ (m & 15);
            *(bf8*)&lds[12288 + m * 128 + gp * 8] = *(bf8*)&tmp[gg * 8];
        }
    }
    __syncthreads();
    {
        int kl = quad * 8;
        bf8 b0 = *(const bf8*)(wstem + (wave * 48 + col) * 1056 + 1024 + kl);
        bf8 b1 = *(const bf8*)(wstem + (wave * 48 + 16 + col) * 1056 + 1024 + kl);
        bf8 b2 = *(const bf8*)(wstem + (wave * 48 + 32 + col) * 1056 + 1024 + kl);
        #pragma unroll
        for (int mt = 0; mt < 4; ++mt) {
            int m = mt * 16 + col;
            bf8 a = *(const bf8*)&lds[12288 + m * 128 + (kl ^ ((m & 15) << 3))];
            acc[mt][0] = MFMA(a, b0, acc[mt][0]);
            acc[mt][1] = MFMA(a, b1, acc[mt][1]);
            acc[mt][2] = MFMA(a, b2, acc[mt][2]);
        }
    }

    // epilogue: + bias, lrelu -> FUSED
    #pragma unroll
    for (int t = 0; t < 3; ++t) {
        int n = wave * 48 + t * 16 + col;
        float bb = bvp[n];
        #pragma unroll
        for (int mt = 0; mt < 4; ++mt)
            #pragma unroll
            for (int r = 0; r < 4; ++r) {
                int m = mt * 16 + quad * 4 + r;
                lds[m * 192 + (n ^ ((m & 7) << 3))] = f2bf(lrelu(acc[mt][t][r] + bb));
            }
    }
    __syncthreads();

    // ============ phase B: GRU ============================================
    {
        int m = tid >> 2, qq = tid & 3;
        const float* hp = hx + (size_t)(S0 + m) * 192 + qq * 48;
        #pragma unroll
        for (int i = 0; i < 6; ++i) {
            f4 d = *(const f4*)(hp + i * 8 + 0);
            f4 d2 = *(const f4*)(hp + i * 8 + 4);
            __align__(16) unsigned short tmp[8];
            #pragma unroll
            for (int u = 0; u < 4; ++u) { tmp[u] = f2bf(d[u]); tmp[4 + u] = f2bf(d2[u]); }
            int gg = qq * 6 + i, gp = gg ^ (m & 7);
            *(bf8*)&lds[12288 + m * 192 + gp * 8] = *(bf8*)tmp;
        }
    }
    __syncthreads();

    #pragma unroll
    for (int t = 0; t < 3; ++t) {
        int j0 = (wave * 3 + t) * 16;
        int j = j0 + col;
        const unsigned short* pih = ws + WIH_OFF + j * 192;
        const unsigned short* phh = ws + WHH_OFF + j * 192;
        f4 g0[4], g1[4], g2[4], g3[4], g4[4], g5[4];
        #pragma unroll
        for (int mt = 0; mt < 4; ++mt) {
            g0[mt] = (f4){0.f,0.f,0.f,0.f}; g1[mt] = g0[mt]; g2[mt] = g0[mt];
            g3[mt] = g0[mt]; g4[mt] = g0[mt]; g5[mt] = g0[mt];
        }
        #pragma unroll
        for (int ks = 0; ks < 6; ++ks) {
            int k0 = ks * 32 + quad * 8;
            bf8 bir = *(const bf8*)(pih + k0);
            bf8 bhr = *(const bf8*)(phh + k0);
            bf8 biz = *(const bf8*)(pih + 36864 + k0);
            bf8 bhz = *(const bf8*)(phh + 36864 + k0);
            bf8 bin = *(const bf8*)(pih + 73728 + k0);
            bf8 bhn = *(const bf8*)(phh + 73728 + k0);
            #pragma unroll
            for (int mt = 0; mt < 4; ++mt) {
                int m = mt * 16 + col;
                int off = m * 192 + (k0 ^ ((m & 7) << 3));
                bf8 aF = *(const bf8*)&lds[off];
                bf8 aH = *(const bf8*)&lds[12288 + off];
                g0[mt] = MFMA(aF, bir, g0[mt]);
                g1[mt] = MFMA(aH, bhr, g1[mt]);
                g2[mt] = MFMA(aF, biz, g2[mt]);
                g3[mt] = MFMA(aH, bhz, g3[mt]);
                g4[mt] = MFMA(aF, bin, g4[mt]);
                g5[mt] = MFMA(aH, bhn, g5[mt]);
            }
        }
        float b_ir = bih[j], b_iz = bih[192 + j], b_in = bih[384 + j];
        float b_hr = bhh[j], b_hz = bhh[192 + j], b_hn = bhh[384 + j];
        #pragma unroll
        for (int mt = 0; mt < 4; ++mt)
            #pragma unroll
            for (int r = 0; r < 4; ++r) {
                int s = mt * 16 + quad * 4 + r;
                float rg = sigm(g0[mt][r] + b_ir + g1[mt][r] + b_hr);
                float zg = sigm(g2[mt][r] + b_iz + g3[mt][r] + b_hz);
                float ng = tanh_(g4[mt][r] + b_in + rg * (g5[mt][r] + b_hn));
                float hxv = hx[(size_t)(S0 + s) * 192 + j];
                float hnew = (1.f - zg) * ng + zg * hxv;
                out[65536 * 4 + (size_t)(S0 + s) * 192 + j] = hnew;
            }
    }
    __syncthreads();   // drain hnew stores (vmcnt(0) before barrier)

    // fc head: thread (s = tid&63, a = tid>>6), re-reads hnew from out (L2-hot)
    {
        int s = tid & 63, a = tid >> 6;
        const float* hp = out + 65536 * 4 + (size_t)(S0 + s) * 192;
        const float* wf = wfc + a * 192;
        float sum = 0.f;
        #pragma unroll 4
        for (int jj = 0; jj < 48; ++jj) {
            f4 hv = *(const f4*)(hp + jj * 4);
            f4 wv = *(const f4*)(wf + jj * 4);
            #pragma unroll
            for (int u = 0; u < 4; ++u) sum += lrelu(hv[u]) * wv[u];
        }
        out[(size_t)(S0 + s) * 4 + a] = sum;
    }
}

// ---------------------------------------------------------------------------
extern "C" void kernel_launch(void* const* d_in, const int* in_sizes, int n_in,
                              void* d_out, int out_size, void* d_ws, size_t ws_size,
                              hipStream_t stream) {
    const float* x     = (const float*)d_in[0];
    const float* v     = (const float*)d_in[1];
    const float* hx    = (const float*)d_in[2];
    const float* w1    = (const float*)d_in[3];
    const float* w2    = (const float*)d_in[4];
    const float* w3    = (const float*)d_in[5];
    const float* wstem = (const float*)d_in[6];
    const float* wvp   = (const float*)d_in[7];
    const float* bvp   = (const float*)d_in[8];
    const float* wih   = (const float*)d_in[9];
    const float* whh   = (const float*)d_in[10];
    const float* bih   = (const float*)d_in[11];
    const float* bhh   = (const float*)d_in[12];
    const float* wfc   = (const float*)d_in[13];
    unsigned short* wsp = (unsigned short*)d_ws;
    unsigned short* c3  = wsp + C3_OFF;
    unsigned short* c2q = wsp + C2Q_OFF;

    prep_weights<<<2016, 256, 0, stream>>>(w2, w3, wstem, wvp, wih, whh, wsp);
    for (int q = 0; q < 4; ++q) {
        conv12<<<1024, 256, 0, stream>>>(x, w1, wsp, c2q, q * 16384);
        conv3k<<<1024, 256, 0, stream>>>(wsp, c2q, c3, q * 16384);
    }
    stem_gru<<<1024, 256, 0, stream>>>(wsp, v, hx, bvp, bih, bhh, wfc, (float*)d_out);
}